// Round 1
// baseline (594.989 us; speedup 1.0000x reference)
//
#include <hip/hip_runtime.h>
#include <math.h>

// ContrastiveTokenLoss: B=2, T=2048, V=32000, CT_LENGTH=0.25 -> ct_len=512,
// PRECED_M_NEGATIVES=0.5 -> win=256. IGNORE_INDEX=-100, PAD_ID=0.
// loss[b,i] = log1p( sum_{j in [i-win, i), tgt[b,j]!=0} exp(x[b,i,tgt[b,j]] - x[b,i,tgt[b,i]]) )
// out = sum(loss * valid_tgt) / max(#valid_tgt, 1)
//
// Fused single-kernel version: per-row blocks compute loss; the last block to
// finish (device-scope atomic ticket) performs the final reduction. Removes
// the second kernel launch + inter-kernel dependency from the graph.
// The 4-byte ticket counter lives in d_ws and is zeroed by a captured
// hipMemsetAsync node (allowed under graph capture; no hipMalloc/hipFree/sync).

#define IGNORE_INDEX (-100)
#define B_ 2
#define T_ 2048
#define V_ 32000
#define CT_LEN 512
#define WIN 256
#define NROWS (B_ * CT_LEN)

__global__ __launch_bounds__(256) void ctl_fused_kernel(
    const float* __restrict__ input,    // (B, T, V) fp32
    const int*   __restrict__ target,   // (B, T) int32
    float* __restrict__ loss_out,       // (NROWS,) per-row loss (0 if invalid)
    float* __restrict__ valid_out,      // (NROWS,) 1.0 if tgt valid else 0.0
    unsigned int* __restrict__ counter, // ticket counter, pre-zeroed
    float* __restrict__ out)            // scalar result
{
    const int r = blockIdx.x;           // row id in [0, NROWS)
    const int b = r >> 9;               // / CT_LEN (512)
    const int i = r & (CT_LEN - 1);
    const int t = threadIdx.x;

    const int tgt_i = target[b * T_ + i];
    const bool valid = (tgt_i != IGNORE_INDEX);
    const int tgt_safe = valid ? tgt_i : 0;

    const float* row = input + ((size_t)b * T_ + (size_t)i) * (size_t)V_;
    // All 256 lanes read the same address -> cache broadcast, negligible cost.
    const float pos = row[tgt_safe];

    float term = 0.0f;
    const int nneg = (i < WIN) ? i : WIN;
    if (valid && t < nneg) {
        const int j = i - 1 - t;
        const int tok = target[b * T_ + j];
        if (tok > 0 && tok < V_) {      // tok==0 is PAD -> not a negative
            term = expf(row[tok] - pos);
        }
    }

    // Wave-64 butterfly reduce, then 4 waves via LDS.
    #pragma unroll
    for (int off = 32; off > 0; off >>= 1)
        term += __shfl_down(term, off, 64);

    __shared__ float wsum[4];
    __shared__ bool amLast;
    const int lane = t & 63;
    const int wave = t >> 6;
    if (lane == 0) wsum[wave] = term;
    __syncthreads();
    if (t == 0) {
        const float s = wsum[0] + wsum[1] + wsum[2] + wsum[3];
        loss_out[r]  = valid ? log1pf(s) : 0.0f;
        valid_out[r] = valid ? 1.0f : 0.0f;
        __threadfence();                         // publish row result device-wide
        const unsigned int ticket = atomicAdd(counter, 1u);  // device scope
        amLast = (ticket == (unsigned int)(NROWS - 1));
    }
    __syncthreads();
    if (!amLast) return;

    // Last block: all other blocks' row results are globally visible
    // (their fence precedes the atomic whose value we observed).
    __threadfence();                             // acquire: invalidate stale cache

    float ls = 0.0f, vs = 0.0f;
    for (int k = t; k < NROWS; k += 256) {
        ls += loss_out[k];
        vs += valid_out[k];
    }
    #pragma unroll
    for (int off = 32; off > 0; off >>= 1) {
        ls += __shfl_down(ls, off, 64);
        vs += __shfl_down(vs, off, 64);
    }
    __shared__ float sl[4], sv[4];
    if (lane == 0) { sl[wave] = ls; sv[wave] = vs; }
    __syncthreads();
    if (t == 0) {
        const float L = sl[0] + sl[1] + sl[2] + sl[3];
        const float C = sv[0] + sv[1] + sv[2] + sv[3];
        const float denom = (C > 1.0f) ? C : 1.0f;
        out[0] = L / denom;
    }
}

extern "C" void kernel_launch(void* const* d_in, const int* in_sizes, int n_in,
                              void* d_out, int out_size, void* d_ws, size_t ws_size,
                              hipStream_t stream) {
    const float* input  = (const float*)d_in[0];   // (B,T,V) fp32
    const int*   target = (const int*)d_in[1];     // (B,T) int32
    float* out = (float*)d_out;

    float* loss_buf  = (float*)d_ws;               // NROWS floats
    float* valid_buf = loss_buf + NROWS;           // NROWS floats
    unsigned int* counter = (unsigned int*)(valid_buf + NROWS); // 1 uint

    // Zero the ticket counter (captured as a memset node in the graph).
    hipMemsetAsync(counter, 0, sizeof(unsigned int), stream);

    ctl_fused_kernel<<<NROWS, 256, 0, stream>>>(input, target, loss_buf,
                                                valid_buf, counter, out);
}

// Round 2
// 556.117 us; speedup vs baseline: 1.0699x; 1.0699x over previous
//
#include <hip/hip_runtime.h>
#include <math.h>

// ContrastiveTokenLoss: B=2, T=2048, V=32000, CT_LENGTH=0.25 -> ct_len=512,
// PRECED_M_NEGATIVES=0.5 -> win=256. IGNORE_INDEX=-100, PAD_ID=0.
// loss[b,i] = log1p( sum_{j in [i-win, i), tgt[b,j]!=0} exp(x[b,i,tgt[b,j]] - x[b,i,tgt[b,i]]) )
// out = sum(loss * valid_tgt) / max(#valid_tgt, 1)
//
// Two-kernel structure (fused last-block version regressed +37us: 1024
// serialized device-scope atomics+threadfences on one line). Rows kernel
// writes per-row loss; finalize recomputes validity from target directly
// (no valid_out round-trip).

#define IGNORE_INDEX (-100)
#define B_ 2
#define T_ 2048
#define V_ 32000
#define CT_LEN 512
#define WIN 256
#define NROWS (B_ * CT_LEN)

// One block (256 threads) per row (b,i). Thread t handles negative index
// j = i-1-t (t < min(i, WIN)). win==blockDim.x so exactly one j per thread.
__global__ __launch_bounds__(256) void ctl_rows_kernel(
    const float* __restrict__ input,   // (B, T, V) fp32
    const int*   __restrict__ target,  // (B, T) int32
    float* __restrict__ loss_out)      // (NROWS,) per-row loss (0 if invalid)
{
    const int r = blockIdx.x;          // row id in [0, NROWS)
    const int b = r >> 9;              // / CT_LEN (512)
    const int i = r & (CT_LEN - 1);
    const int t = threadIdx.x;

    const int tgt_i = target[b * T_ + i];
    const bool valid = (tgt_i != IGNORE_INDEX);
    const int tgt_safe = valid ? tgt_i : 0;

    const float* row = input + ((size_t)b * T_ + (size_t)i) * (size_t)V_;
    // All 256 lanes read the same address -> cache broadcast, negligible cost.
    const float pos = row[tgt_safe];

    float term = 0.0f;
    const int nneg = (i < WIN) ? i : WIN;
    if (valid && t < nneg) {
        const int j = i - 1 - t;
        const int tok = target[b * T_ + j];
        if (tok > 0 && tok < V_) {     // tok==0 is PAD -> not a negative
            term = expf(row[tok] - pos);
        }
    }

    // Wave-64 butterfly reduce, then 4 waves via LDS.
    #pragma unroll
    for (int off = 32; off > 0; off >>= 1)
        term += __shfl_down(term, off, 64);

    __shared__ float wsum[4];
    const int lane = t & 63;
    const int wave = t >> 6;
    if (lane == 0) wsum[wave] = term;
    __syncthreads();
    if (t == 0) {
        const float s = wsum[0] + wsum[1] + wsum[2] + wsum[3];
        loss_out[r] = valid ? log1pf(s) : 0.0f;
    }
}

// Single-block final reduction over NROWS rows. Validity recomputed from
// target (L2-resident 4 KB) instead of a second workspace array.
__global__ __launch_bounds__(1024) void ctl_finalize_kernel(
    const float* __restrict__ loss,
    const int*   __restrict__ target,
    float* __restrict__ out)
{
    const int t = threadIdx.x;
    float ls = 0.0f, vs = 0.0f;
    for (int k = t; k < NROWS; k += 1024) {
        const int b = k >> 9;
        const int i = k & (CT_LEN - 1);
        const bool valid = (target[b * T_ + i] != IGNORE_INDEX);
        ls += loss[k];                 // loss[k] is 0 for invalid rows
        vs += valid ? 1.0f : 0.0f;
    }
    #pragma unroll
    for (int off = 32; off > 0; off >>= 1) {
        ls += __shfl_down(ls, off, 64);
        vs += __shfl_down(vs, off, 64);
    }
    __shared__ float sl[16], sv[16];
    const int lane = t & 63;
    const int wave = t >> 6;
    if (lane == 0) { sl[wave] = ls; sv[wave] = vs; }
    __syncthreads();
    if (t == 0) {
        float L = 0.0f, C = 0.0f;
        #pragma unroll
        for (int w = 0; w < 16; ++w) { L += sl[w]; C += sv[w]; }
        const float denom = (C > 1.0f) ? C : 1.0f;
        out[0] = L / denom;
    }
}

extern "C" void kernel_launch(void* const* d_in, const int* in_sizes, int n_in,
                              void* d_out, int out_size, void* d_ws, size_t ws_size,
                              hipStream_t stream) {
    const float* input  = (const float*)d_in[0];   // (B,T,V) fp32
    const int*   target = (const int*)d_in[1];     // (B,T) int32
    float* out = (float*)d_out;

    float* loss_buf = (float*)d_ws;                // NROWS floats (4 KiB)

    ctl_rows_kernel<<<NROWS, 256, 0, stream>>>(input, target, loss_buf);
    ctl_finalize_kernel<<<1, 1024, 0, stream>>>(loss_buf, target, out);
}